// Round 4
// baseline (310.904 us; speedup 1.0000x reference)
//
#include <hip/hip_runtime.h>
#include <hip/hip_bf16.h>

// B=8, LQ=LK=2048, D=128, fp32 in/out, softmax(qk*scale) @ V.
// bf16x3 split-precision QK^T (fp32-accurate logits), fp32 online softmax,
// bf16 PV. K-split + merge.
// R1: 1-deep reg prefetch, 64-row K tiles, 2 blocks/CU (88us flash).
// R2: FAILED (127us): V^T direct-from-global exposed PV latency.
// R3: FAILED (98us): 32-row tiles doubled per-iter overhead; occupancy not
//     the limiter -- per-iteration serial softmax + P LDS round-trip is.
// R4: swapped QK^T (mfma(K,Q)) => each lane owns ONE q-row, 16 k-values.
//     k-permutation sigma(t,m)=32(t&1)+8(m>>2)+4(t>>1)+(m&3) on the A-frag
//     read row makes the lane's P values exactly its PV A-fragment: softmax
//     32 shuffles -> 4, P LDS round-trip eliminated, lds_p freed =>
//     52KB LDS => 3 blocks/CU at 64-row tiles. KSPLIT=3 (768 blocks), scale
//     via 4x dwordx4.

typedef float          f32x4 __attribute__((ext_vector_type(4)));
typedef short          s16x8 __attribute__((ext_vector_type(8)));
typedef unsigned int   u32x4 __attribute__((ext_vector_type(4)));
typedef unsigned short u16x4 __attribute__((ext_vector_type(4)));

#define LOG2E 1.4426950408889634f

__device__ __forceinline__ float fast_exp2(float x) {
#if __has_builtin(__builtin_amdgcn_exp2f)
    return __builtin_amdgcn_exp2f(x);
#else
    return exp2f(x);
#endif
}

__device__ __forceinline__ unsigned short f2bf(float x) {
    return __builtin_bit_cast(unsigned short, __float2bfloat16(x));
}
__device__ __forceinline__ float bf2f(unsigned short u) {
    return __bfloat162float(__builtin_bit_cast(__hip_bfloat16, u));
}

// ---------------- fused pre-pass ----------------
__global__ void prep(const float* __restrict__ q,
                     const float* __restrict__ k,
                     const float* __restrict__ v,
                     unsigned short* __restrict__ qh,
                     unsigned short* __restrict__ ql,
                     unsigned short* __restrict__ kh,
                     unsigned short* __restrict__ kl,
                     unsigned short* __restrict__ vt) {
    __shared__ unsigned short tile[64 * 132];
    const int bb  = blockIdx.x;
    const int tid = threadIdx.x;

    if (bb < 4096) {   // ---- conv_split for Q or K ----
        const bool isq = bb < 2048;
        const float* src = isq ? q : k;
        unsigned short* hi = isq ? qh : kh;
        unsigned short* lo = isq ? ql : kl;
        const int i = (isq ? bb : bb - 2048) * 256 + tid;
        const float4 val = ((const float4*)src)[i];
        float f[4] = {val.x, val.y, val.z, val.w};
        u16x4 h, l;
#pragma unroll
        for (int j = 0; j < 4; ++j) {
            unsigned short hb = f2bf(f[j]);
            h[j] = hb;
            l[j] = f2bf(f[j] - bf2f(hb));
        }
        ((u16x4*)hi)[i] = h;
        ((u16x4*)lo)[i] = l;
        return;
    }

    // ---- transpose_v ----
    const int tb = bb - 4096;
    const int b  = tb & 7;
    const int k0 = (tb >> 3) * 64;
#pragma unroll
    for (int p = 0; p < 8; ++p) {
        int idx  = p * 256 + tid;
        int kk   = idx >> 5;
        int dblk = idx & 31;
        float4 val = ((const float4*)v)[((b * 2048 + k0 + kk) * 128 + dblk * 4) >> 2];
        u16x4 t4;
        t4[0] = f2bf(val.x); t4[1] = f2bf(val.y);
        t4[2] = f2bf(val.z); t4[3] = f2bf(val.w);
        *(u16x4*)&tile[kk * 132 + dblk * 4] = t4;
    }
    __syncthreads();
#pragma unroll
    for (int p = 0; p < 4; ++p) {
        int idx = p * 256 + tid;
        int d   = idx >> 3;
        int k8  = idx & 7;
        u16x4 a, c;
#pragma unroll
        for (int j = 0; j < 4; ++j) a[j] = tile[(k8 * 8 + j) * 132 + d];
#pragma unroll
        for (int j = 0; j < 4; ++j) c[j] = tile[(k8 * 8 + 4 + j) * 132 + d];
        unsigned short* outp = vt + (b * 128 + d) * 2048 + k0 + k8 * 8;
        *(u16x4*)outp       = a;
        *(u16x4*)(outp + 4) = c;
    }
}

// ---------------- flash attention main kernel ----------------
// LDS: kh 64*136*2 = 17408, kl 17408, vt 128*72*2 = 18432 => 53248 B (52KB)
#define KHS 136
#define VTS 72

template <int KSPLIT>
__global__ __launch_bounds__(256, 3)
void flash_fwd(const unsigned short* __restrict__ qh_g,
               const unsigned short* __restrict__ ql_g,
               const unsigned short* __restrict__ kh_g,
               const unsigned short* __restrict__ kl_g,
               const unsigned short* __restrict__ vt_g,
               const float* __restrict__ scale_g,
               float* __restrict__ opart,
               float* __restrict__ mpart,
               float* __restrict__ lpart) {
    __shared__ unsigned short lds_kh[64 * KHS];
    __shared__ unsigned short lds_kl[64 * KHS];
    __shared__ unsigned short lds_vt[128 * VTS];

    const int tid  = threadIdx.x;
    const int wave = tid >> 6;
    const int lane = tid & 63;
    const int c    = lane & 15;
    const int g    = lane >> 4;

    const int bid   = blockIdx.x;
    const int b     = bid & 7;            // batch <-> XCD affinity
    const int qt    = (bid >> 3) & 31;
    const int ks    = bid >> 8;           // k-split index
    const int q0    = qt * 64;

    const int PER   = (32 + KSPLIT - 1) / KSPLIT;   // k-tiles per split
    const int kt0   = ks * PER;
    const int NIT   = min(PER, 32 - kt0);
    const int kbase = kt0 * 64;

    // staging thread mappings (global->reg->LDS)
    const int srow = tid >> 4, sc8 = tid & 15;   // K: 16 rows/pass
    const int sdv  = tid >> 3, sk8 = tid & 7;    // V^T: 32 d-rows/pass

    // sigma read-row bases for the QK A-fragment (per tile t: +{0,32,4,36})
    const int rc = 8 * (c >> 2) + (c & 3);

    // Q fragments (B-operand now; layout unchanged: col=c -> q row, k=g*8+j -> d)
    s16x8 qh[4], ql[4];
    {
        const int qrow = b * 2048 + q0 + wave * 16 + c;
#pragma unroll
        for (int kstep = 0; kstep < 4; ++kstep) {
            int idx = qrow * 16 + kstep * 4 + g;
            qh[kstep] = __builtin_bit_cast(s16x8, ((const u32x4*)qh_g)[idx]);
            ql[kstep] = __builtin_bit_cast(s16x8, ((const u32x4*)ql_g)[idx]);
        }
    }

    f32x4 oacc[8];
#pragma unroll
    for (int t = 0; t < 8; ++t) oacc[t] = (f32x4){0.f, 0.f, 0.f, 0.f};
    float m2 = -INFINITY, ln = 0.f;   // per-lane: q-row = q0+wave*16+c

    // ---- prefetch state (one iteration deep) ----
    u32x4 pk[4], pl[4], pv[4];
    float4 scn[4];
    // scale base: row = q (c), col offset includes 8*g; per-tile +{0,32,4,36}
    const size_t scb = (size_t)(b * 2048 + q0 + wave * 16 + c) * 2048 + 8 * g;

    {
        const int k0 = kbase;
#pragma unroll
        for (int p = 0; p < 4; ++p) {
            int gidx = (b * 2048 + k0 + p * 16 + srow) * 16 + sc8;
            pk[p] = ((const u32x4*)kh_g)[gidx];
            pl[p] = ((const u32x4*)kl_g)[gidx];
            int vidx = (b * 128 + p * 32 + sdv) * 256 + (k0 >> 3) + sk8;
            pv[p] = ((const u32x4*)vt_g)[vidx];
        }
        scn[0] = *(const float4*)&scale_g[scb + k0 + 0];
        scn[1] = *(const float4*)&scale_g[scb + k0 + 32];
        scn[2] = *(const float4*)&scale_g[scb + k0 + 4];
        scn[3] = *(const float4*)&scale_g[scb + k0 + 36];
    }

    for (int kc = 0; kc < NIT; ++kc) {
        const int k0 = kbase + kc * 64;

        // ---- commit prefetched tiles to LDS ----
        __syncthreads();
#pragma unroll
        for (int p = 0; p < 4; ++p) {
            *(u32x4*)&lds_kh[(p * 16 + srow) * KHS + sc8 * 8] = pk[p];
            *(u32x4*)&lds_kl[(p * 16 + srow) * KHS + sc8 * 8] = pl[p];
            *(u32x4*)&lds_vt[(p * 32 + sdv) * VTS + sk8 * 8]  = pv[p];
        }
        __syncthreads();

        // ---- consume prefetched scale ----
        float scl[4][4];
#pragma unroll
        for (int t = 0; t < 4; ++t) {
            scl[t][0] = scn[t].x * LOG2E; scl[t][1] = scn[t].y * LOG2E;
            scl[t][2] = scn[t].z * LOG2E; scl[t][3] = scn[t].w * LOG2E;
        }

        // ---- issue next iteration's loads (overlap with compute) ----
        if (kc < NIT - 1) {
            const int kn = k0 + 64;
#pragma unroll
            for (int p = 0; p < 4; ++p) {
                int gidx = (b * 2048 + kn + p * 16 + srow) * 16 + sc8;
                pk[p] = ((const u32x4*)kh_g)[gidx];
                pl[p] = ((const u32x4*)kl_g)[gidx];
                int vidx = (b * 128 + p * 32 + sdv) * 256 + (kn >> 3) + sk8;
                pv[p] = ((const u32x4*)vt_g)[vidx];
            }
            scn[0] = *(const float4*)&scale_g[scb + kn + 0];
            scn[1] = *(const float4*)&scale_g[scb + kn + 32];
            scn[2] = *(const float4*)&scale_g[scb + kn + 4];
            scn[3] = *(const float4*)&scale_g[scb + kn + 36];
        }

        // ---- S^T = K Q^T (swapped operands), bf16x3 split ----
        // A-frag read row for tile t: sigma => rc + {0,32,4,36}[t]
        f32x4 s[4];
#pragma unroll
        for (int t = 0; t < 4; ++t) s[t] = (f32x4){0.f, 0.f, 0.f, 0.f};
#pragma unroll
        for (int kstep = 0; kstep < 4; ++kstep) {
            const int co = kstep * 32 + g * 8;
            {   // t=0: row rc
                s16x8 bh = *(const s16x8*)&lds_kh[(rc + 0) * KHS + co];
                s16x8 bl = *(const s16x8*)&lds_kl[(rc + 0) * KHS + co];
                s[0] = __builtin_amdgcn_mfma_f32_16x16x32_bf16(bh, qh[kstep], s[0], 0, 0, 0);
                s[0] = __builtin_amdgcn_mfma_f32_16x16x32_bf16(bh, ql[kstep], s[0], 0, 0, 0);
                s[0] = __builtin_amdgcn_mfma_f32_16x16x32_bf16(bl, qh[kstep], s[0], 0, 0, 0);
            }
            {   // t=1: row rc+32
                s16x8 bh = *(const s16x8*)&lds_kh[(rc + 32) * KHS + co];
                s16x8 bl = *(const s16x8*)&lds_kl[(rc + 32) * KHS + co];
                s[1] = __builtin_amdgcn_mfma_f32_16x16x32_bf16(bh, qh[kstep], s[1], 0, 0, 0);
                s[1] = __builtin_amdgcn_mfma_f32_16x16x32_bf16(bh, ql[kstep], s[1], 0, 0, 0);
                s[1] = __builtin_amdgcn_mfma_f32_16x16x32_bf16(bl, qh[kstep], s[1], 0, 0, 0);
            }
            {   // t=2: row rc+4
                s16x8 bh = *(const s16x8*)&lds_kh[(rc + 4) * KHS + co];
                s16x8 bl = *(const s16x8*)&lds_kl[(rc + 4) * KHS + co];
                s[2] = __builtin_amdgcn_mfma_f32_16x16x32_bf16(bh, qh[kstep], s[2], 0, 0, 0);
                s[2] = __builtin_amdgcn_mfma_f32_16x16x32_bf16(bh, ql[kstep], s[2], 0, 0, 0);
                s[2] = __builtin_amdgcn_mfma_f32_16x16x32_bf16(bl, qh[kstep], s[2], 0, 0, 0);
            }
            {   // t=3: row rc+36
                s16x8 bh = *(const s16x8*)&lds_kh[(rc + 36) * KHS + co];
                s16x8 bl = *(const s16x8*)&lds_kl[(rc + 36) * KHS + co];
                s[3] = __builtin_amdgcn_mfma_f32_16x16x32_bf16(bh, qh[kstep], s[3], 0, 0, 0);
                s[3] = __builtin_amdgcn_mfma_f32_16x16x32_bf16(bh, ql[kstep], s[3], 0, 0, 0);
                s[3] = __builtin_amdgcn_mfma_f32_16x16x32_bf16(bl, qh[kstep], s[3], 0, 0, 0);
            }
        }

        // ---- online softmax: lane owns row q=c, 16 k-values in-register ----
        float p[4][4];
        float mx = -INFINITY;
#pragma unroll
        for (int t = 0; t < 4; ++t)
#pragma unroll
            for (int r = 0; r < 4; ++r) {
                float v = s[t][r] * scl[t][r];
                p[t][r] = v;
                mx = fmaxf(mx, v);
            }
        mx = fmaxf(mx, __shfl_xor(mx, 16));
        mx = fmaxf(mx, __shfl_xor(mx, 32));
        const float mn = fmaxf(m2, mx);
        const float al = fast_exp2(m2 - mn);   // first iter: exp2(-inf)=0
        m2 = mn;
        float rs = 0.f;
#pragma unroll
        for (int t = 0; t < 4; ++t)
#pragma unroll
            for (int r = 0; r < 4; ++r) {
                float pe = fast_exp2(p[t][r] - mn);
                p[t][r] = pe;
                rs += pe;
            }
        rs += __shfl_xor(rs, 16);
        rs += __shfl_xor(rs, 32);
        ln = ln * al + rs;

        // broadcast al to this lane's oacc rows (q = g*4+r)
        float alr[4];
#pragma unroll
        for (int r = 0; r < 4; ++r)
            alr[r] = __shfl(al, (lane & 48) | (g * 4 + r));
#pragma unroll
        for (int t2 = 0; t2 < 8; ++t2)
#pragma unroll
            for (int r = 0; r < 4; ++r) oacc[t2][r] *= alr[r];

        // ---- pack P: lane's 16 values ARE its PV A-fragment (via sigma) ----
        unsigned int w[8];
#pragma unroll
        for (int t = 0; t < 4; ++t)
#pragma unroll
            for (int h = 0; h < 2; ++h)
                w[t * 2 + h] = (unsigned int)f2bf(p[t][2 * h]) |
                               ((unsigned int)f2bf(p[t][2 * h + 1]) << 16);
        u32x4 af0 = {w[0], w[1], w[4], w[5]};
        u32x4 af1 = {w[2], w[3], w[6], w[7]};

        // ---- O += P V ----
        {
            s16x8 a0 = __builtin_bit_cast(s16x8, af0);
#pragma unroll
            for (int t2 = 0; t2 < 8; ++t2) {
                s16x8 bv = *(const s16x8*)&lds_vt[(t2 * 16 + c) * VTS + g * 8];
                oacc[t2] = __builtin_amdgcn_mfma_f32_16x16x32_bf16(a0, bv, oacc[t2], 0, 0, 0);
            }
            s16x8 a1 = __builtin_bit_cast(s16x8, af1);
#pragma unroll
            for (int t2 = 0; t2 < 8; ++t2) {
                s16x8 bv = *(const s16x8*)&lds_vt[(t2 * 16 + c) * VTS + 32 + g * 8];
                oacc[t2] = __builtin_amdgcn_mfma_f32_16x16x32_bf16(a1, bv, oacc[t2], 0, 0, 0);
            }
        }
    }

    // ---- write unnormalized partials + stats ----
    {
        const int rowb = (ks * 8 + b) * 2048 + q0 + wave * 16;
#pragma unroll
        for (int t2 = 0; t2 < 8; ++t2)
#pragma unroll
            for (int r = 0; r < 4; ++r)
                opart[(size_t)(rowb + g * 4 + r) * 128 + t2 * 16 + c] = oacc[t2][r];
        if (g == 0) {   // one lane per q-row (lane = c)
            mpart[rowb + c] = m2;
            lpart[rowb + c] = ln;
        }
    }
}

// ---------------- merge the k-split partials ----------------
template <int KSPLIT>
__global__ void merge_parts(const float* __restrict__ opart,
                            const float* __restrict__ mpart,
                            const float* __restrict__ lpart,
                            float* __restrict__ out) {
    const int row = blockIdx.x;
    const int d   = threadIdx.x;
    float m[KSPLIT], l[KSPLIT];
    float M = -INFINITY;
#pragma unroll
    for (int i = 0; i < KSPLIT; ++i) {
        m[i] = mpart[i * 16384 + row];
        l[i] = lpart[i * 16384 + row];
        M = fmaxf(M, m[i]);
    }
    float denom = 0.f, acc = 0.f;
    const size_t base = (size_t)row * 128 + d;
#pragma unroll
    for (int i = 0; i < KSPLIT; ++i) {
        const float a = fast_exp2(m[i] - M);
        denom += a * l[i];
        acc   += a * opart[(size_t)i * 16384 * 128 + base];
    }
    out[base] = acc / denom;
}

extern "C" void kernel_launch(void* const* d_in, const int* in_sizes, int n_in,
                              void* d_out, int out_size, void* d_ws, size_t ws_size,
                              hipStream_t stream) {
    const float* q  = (const float*)d_in[0];
    const float* k  = (const float*)d_in[1];
    const float* v  = (const float*)d_in[2];
    const float* sc = (const float*)d_in[3];
    float* out = (float*)d_out;

    char* ws = (char*)d_ws;
    const size_t MB = 1024 * 1024;
    unsigned short* qh = (unsigned short*)(ws);
    unsigned short* ql = (unsigned short*)(ws + 4 * MB);
    unsigned short* kh = (unsigned short*)(ws + 8 * MB);
    unsigned short* kl = (unsigned short*)(ws + 12 * MB);
    unsigned short* vt = (unsigned short*)(ws + 16 * MB);

    prep<<<4352, 256, 0, stream>>>(q, k, v, qh, ql, kh, kl, vt);

    // KSPLIT=3: opart 24MB @20MB, m/l @44MB. Need ~44.5MB.
    const size_t need3 = 44 * MB + 512 * 1024;
    if (ws_size >= need3) {
        float* opart = (float*)(ws + 20 * MB);                 // [3][16384][128]
        float* mpart = (float*)(ws + 44 * MB);                 // [3][16384]
        float* lpart = (float*)(ws + 44 * MB + 256 * 1024);    // [3][16384]
        flash_fwd<3><<<768, 256, 0, stream>>>(qh, ql, kh, kl, vt, sc, opart, mpart, lpart);
        merge_parts<3><<<16384, 128, 0, stream>>>(opart, mpart, lpart, out);
    } else {
        float* opart = (float*)(ws + 20 * MB);                 // [2][16384][128]
        float* mpart = (float*)(ws + 36 * MB);                 // [2][16384]
        float* lpart = (float*)(ws + 36 * MB + 128 * 1024);    // [2][16384]
        flash_fwd<2><<<512, 256, 0, stream>>>(qh, ql, kh, kl, vt, sc, opart, mpart, lpart);
        merge_parts<2><<<16384, 128, 0, stream>>>(opart, mpart, lpart, out);
    }
}

// Round 5
// 257.120 us; speedup vs baseline: 1.2092x; 1.2092x over previous
//
#include <hip/hip_runtime.h>
#include <hip/hip_bf16.h>

// B=8, LQ=LK=2048, D=128, fp32 in/out, softmax(qk*scale) @ V.
// bf16x3 split-precision QK^T (fp32-accurate logits), fp32 online softmax,
// bf16 PV. K-split + merge.
// R1: 1-deep reg prefetch, 64-row K tiles, 2 blocks/CU (88us flash).
// R2: FAILED (127us): V^T direct-from-global exposed PV latency.
// R3: FAILED (98us): 32-row tiles doubled per-iter overhead.
// R4: swapped QK^T + sigma k-permutation => lane-local softmax (4 shuffles),
//     P stays in registers (PV A-frag direct). CORRECT but launch_bounds(256,3)
//     capped VGPR at 170 < ~200 needed => compiler spilled arrays to scratch
//     (WRITE_SIZE 189MB, VGPR reported 84). 139us.
// R5: same algorithm, un-spilled: launch_bounds(256,2) (VGPR cap 256),
//     KSPLIT=2 (512 blocks = 2/CU, the VGPR-limited residency).

typedef float          f32x4 __attribute__((ext_vector_type(4)));
typedef short          s16x8 __attribute__((ext_vector_type(8)));
typedef unsigned int   u32x4 __attribute__((ext_vector_type(4)));
typedef unsigned short u16x4 __attribute__((ext_vector_type(4)));

#define LOG2E 1.4426950408889634f

__device__ __forceinline__ float fast_exp2(float x) {
#if __has_builtin(__builtin_amdgcn_exp2f)
    return __builtin_amdgcn_exp2f(x);
#else
    return exp2f(x);
#endif
}

__device__ __forceinline__ unsigned short f2bf(float x) {
    return __builtin_bit_cast(unsigned short, __float2bfloat16(x));
}
__device__ __forceinline__ float bf2f(unsigned short u) {
    return __bfloat162float(__builtin_bit_cast(__hip_bfloat16, u));
}

// ---------------- fused pre-pass ----------------
__global__ void prep(const float* __restrict__ q,
                     const float* __restrict__ k,
                     const float* __restrict__ v,
                     unsigned short* __restrict__ qh,
                     unsigned short* __restrict__ ql,
                     unsigned short* __restrict__ kh,
                     unsigned short* __restrict__ kl,
                     unsigned short* __restrict__ vt) {
    __shared__ unsigned short tile[64 * 132];
    const int bb  = blockIdx.x;
    const int tid = threadIdx.x;

    if (bb < 4096) {   // ---- conv_split for Q or K ----
        const bool isq = bb < 2048;
        const float* src = isq ? q : k;
        unsigned short* hi = isq ? qh : kh;
        unsigned short* lo = isq ? ql : kl;
        const int i = (isq ? bb : bb - 2048) * 256 + tid;
        const float4 val = ((const float4*)src)[i];
        float f[4] = {val.x, val.y, val.z, val.w};
        u16x4 h, l;
#pragma unroll
        for (int j = 0; j < 4; ++j) {
            unsigned short hb = f2bf(f[j]);
            h[j] = hb;
            l[j] = f2bf(f[j] - bf2f(hb));
        }
        ((u16x4*)hi)[i] = h;
        ((u16x4*)lo)[i] = l;
        return;
    }

    // ---- transpose_v ----
    const int tb = bb - 4096;
    const int b  = tb & 7;
    const int k0 = (tb >> 3) * 64;
#pragma unroll
    for (int p = 0; p < 8; ++p) {
        int idx  = p * 256 + tid;
        int kk   = idx >> 5;
        int dblk = idx & 31;
        float4 val = ((const float4*)v)[((b * 2048 + k0 + kk) * 128 + dblk * 4) >> 2];
        u16x4 t4;
        t4[0] = f2bf(val.x); t4[1] = f2bf(val.y);
        t4[2] = f2bf(val.z); t4[3] = f2bf(val.w);
        *(u16x4*)&tile[kk * 132 + dblk * 4] = t4;
    }
    __syncthreads();
#pragma unroll
    for (int p = 0; p < 4; ++p) {
        int idx = p * 256 + tid;
        int d   = idx >> 3;
        int k8  = idx & 7;
        u16x4 a, c;
#pragma unroll
        for (int j = 0; j < 4; ++j) a[j] = tile[(k8 * 8 + j) * 132 + d];
#pragma unroll
        for (int j = 0; j < 4; ++j) c[j] = tile[(k8 * 8 + 4 + j) * 132 + d];
        unsigned short* outp = vt + (b * 128 + d) * 2048 + k0 + k8 * 8;
        *(u16x4*)outp       = a;
        *(u16x4*)(outp + 4) = c;
    }
}

// ---------------- flash attention main kernel ----------------
// LDS: kh 64*136*2 = 17408, kl 17408, vt 128*72*2 = 18432 => 53248 B (52KB)
#define KHS 136
#define VTS 72

template <int KSPLIT>
__global__ __launch_bounds__(256, 2)
void flash_fwd(const unsigned short* __restrict__ qh_g,
               const unsigned short* __restrict__ ql_g,
               const unsigned short* __restrict__ kh_g,
               const unsigned short* __restrict__ kl_g,
               const unsigned short* __restrict__ vt_g,
               const float* __restrict__ scale_g,
               float* __restrict__ opart,
               float* __restrict__ mpart,
               float* __restrict__ lpart) {
    __shared__ unsigned short lds_kh[64 * KHS];
    __shared__ unsigned short lds_kl[64 * KHS];
    __shared__ unsigned short lds_vt[128 * VTS];

    const int tid  = threadIdx.x;
    const int wave = tid >> 6;
    const int lane = tid & 63;
    const int c    = lane & 15;
    const int g    = lane >> 4;

    const int bid   = blockIdx.x;
    const int b     = bid & 7;            // batch <-> XCD affinity
    const int qt    = (bid >> 3) & 31;
    const int ks    = bid >> 8;           // k-split index
    const int q0    = qt * 64;

    const int PER   = 32 / KSPLIT;        // k-tiles per split
    const int kt0   = ks * PER;
    const int NIT   = PER;
    const int kbase = kt0 * 64;

    // staging thread mappings (global->reg->LDS)
    const int srow = tid >> 4, sc8 = tid & 15;   // K: 16 rows/pass
    const int sdv  = tid >> 3, sk8 = tid & 7;    // V^T: 32 d-rows/pass

    // sigma read-row bases for the QK A-fragment (per tile t: +{0,32,4,36})
    const int rc = 8 * (c >> 2) + (c & 3);

    // Q fragments (B-operand now; layout: col=c -> q row, k=g*8+j -> d)
    s16x8 qh[4], ql[4];
    {
        const int qrow = b * 2048 + q0 + wave * 16 + c;
#pragma unroll
        for (int kstep = 0; kstep < 4; ++kstep) {
            int idx = qrow * 16 + kstep * 4 + g;
            qh[kstep] = __builtin_bit_cast(s16x8, ((const u32x4*)qh_g)[idx]);
            ql[kstep] = __builtin_bit_cast(s16x8, ((const u32x4*)ql_g)[idx]);
        }
    }

    f32x4 oacc[8];
#pragma unroll
    for (int t = 0; t < 8; ++t) oacc[t] = (f32x4){0.f, 0.f, 0.f, 0.f};
    float m2 = -INFINITY, ln = 0.f;   // per-lane: q-row = q0+wave*16+c

    // ---- prefetch state (one iteration deep) ----
    u32x4 pk[4], pl[4], pv[4];
    float4 scn[4];
    // scale base: row = q (c), col offset includes 8*g; per-tile +{0,32,4,36}
    const size_t scb = (size_t)(b * 2048 + q0 + wave * 16 + c) * 2048 + 8 * g;

    {
        const int k0 = kbase;
#pragma unroll
        for (int p = 0; p < 4; ++p) {
            int gidx = (b * 2048 + k0 + p * 16 + srow) * 16 + sc8;
            pk[p] = ((const u32x4*)kh_g)[gidx];
            pl[p] = ((const u32x4*)kl_g)[gidx];
            int vidx = (b * 128 + p * 32 + sdv) * 256 + (k0 >> 3) + sk8;
            pv[p] = ((const u32x4*)vt_g)[vidx];
        }
        scn[0] = *(const float4*)&scale_g[scb + k0 + 0];
        scn[1] = *(const float4*)&scale_g[scb + k0 + 32];
        scn[2] = *(const float4*)&scale_g[scb + k0 + 4];
        scn[3] = *(const float4*)&scale_g[scb + k0 + 36];
    }

    for (int kc = 0; kc < NIT; ++kc) {
        const int k0 = kbase + kc * 64;

        // ---- commit prefetched tiles to LDS ----
        __syncthreads();
#pragma unroll
        for (int p = 0; p < 4; ++p) {
            *(u32x4*)&lds_kh[(p * 16 + srow) * KHS + sc8 * 8] = pk[p];
            *(u32x4*)&lds_kl[(p * 16 + srow) * KHS + sc8 * 8] = pl[p];
            *(u32x4*)&lds_vt[(p * 32 + sdv) * VTS + sk8 * 8]  = pv[p];
        }
        __syncthreads();

        // ---- consume prefetched scale ----
        float scl[4][4];
#pragma unroll
        for (int t = 0; t < 4; ++t) {
            scl[t][0] = scn[t].x * LOG2E; scl[t][1] = scn[t].y * LOG2E;
            scl[t][2] = scn[t].z * LOG2E; scl[t][3] = scn[t].w * LOG2E;
        }

        // ---- issue next iteration's loads (overlap with compute) ----
        if (kc < NIT - 1) {
            const int kn = k0 + 64;
#pragma unroll
            for (int p = 0; p < 4; ++p) {
                int gidx = (b * 2048 + kn + p * 16 + srow) * 16 + sc8;
                pk[p] = ((const u32x4*)kh_g)[gidx];
                pl[p] = ((const u32x4*)kl_g)[gidx];
                int vidx = (b * 128 + p * 32 + sdv) * 256 + (kn >> 3) + sk8;
                pv[p] = ((const u32x4*)vt_g)[vidx];
            }
            scn[0] = *(const float4*)&scale_g[scb + kn + 0];
            scn[1] = *(const float4*)&scale_g[scb + kn + 32];
            scn[2] = *(const float4*)&scale_g[scb + kn + 4];
            scn[3] = *(const float4*)&scale_g[scb + kn + 36];
        }

        // ---- S^T = K Q^T (swapped operands), bf16x3 split ----
        // A-frag read row for tile t: sigma => rc + {0,32,4,36}[t]
        f32x4 s[4];
#pragma unroll
        for (int t = 0; t < 4; ++t) s[t] = (f32x4){0.f, 0.f, 0.f, 0.f};
#pragma unroll
        for (int kstep = 0; kstep < 4; ++kstep) {
            const int co = kstep * 32 + g * 8;
            {   // t=0: row rc
                s16x8 bh = *(const s16x8*)&lds_kh[(rc + 0) * KHS + co];
                s16x8 bl = *(const s16x8*)&lds_kl[(rc + 0) * KHS + co];
                s[0] = __builtin_amdgcn_mfma_f32_16x16x32_bf16(bh, qh[kstep], s[0], 0, 0, 0);
                s[0] = __builtin_amdgcn_mfma_f32_16x16x32_bf16(bh, ql[kstep], s[0], 0, 0, 0);
                s[0] = __builtin_amdgcn_mfma_f32_16x16x32_bf16(bl, qh[kstep], s[0], 0, 0, 0);
            }
            {   // t=1: row rc+32
                s16x8 bh = *(const s16x8*)&lds_kh[(rc + 32) * KHS + co];
                s16x8 bl = *(const s16x8*)&lds_kl[(rc + 32) * KHS + co];
                s[1] = __builtin_amdgcn_mfma_f32_16x16x32_bf16(bh, qh[kstep], s[1], 0, 0, 0);
                s[1] = __builtin_amdgcn_mfma_f32_16x16x32_bf16(bh, ql[kstep], s[1], 0, 0, 0);
                s[1] = __builtin_amdgcn_mfma_f32_16x16x32_bf16(bl, qh[kstep], s[1], 0, 0, 0);
            }
            {   // t=2: row rc+4
                s16x8 bh = *(const s16x8*)&lds_kh[(rc + 4) * KHS + co];
                s16x8 bl = *(const s16x8*)&lds_kl[(rc + 4) * KHS + co];
                s[2] = __builtin_amdgcn_mfma_f32_16x16x32_bf16(bh, qh[kstep], s[2], 0, 0, 0);
                s[2] = __builtin_amdgcn_mfma_f32_16x16x32_bf16(bh, ql[kstep], s[2], 0, 0, 0);
                s[2] = __builtin_amdgcn_mfma_f32_16x16x32_bf16(bl, qh[kstep], s[2], 0, 0, 0);
            }
            {   // t=3: row rc+36
                s16x8 bh = *(const s16x8*)&lds_kh[(rc + 36) * KHS + co];
                s16x8 bl = *(const s16x8*)&lds_kl[(rc + 36) * KHS + co];
                s[3] = __builtin_amdgcn_mfma_f32_16x16x32_bf16(bh, qh[kstep], s[3], 0, 0, 0);
                s[3] = __builtin_amdgcn_mfma_f32_16x16x32_bf16(bh, ql[kstep], s[3], 0, 0, 0);
                s[3] = __builtin_amdgcn_mfma_f32_16x16x32_bf16(bl, qh[kstep], s[3], 0, 0, 0);
            }
        }

        // ---- online softmax: lane owns row q=c, 16 k-values in-register ----
        float p[4][4];
        float mx = -INFINITY;
#pragma unroll
        for (int t = 0; t < 4; ++t)
#pragma unroll
            for (int r = 0; r < 4; ++r) {
                float v = s[t][r] * scl[t][r];
                p[t][r] = v;
                mx = fmaxf(mx, v);
            }
        mx = fmaxf(mx, __shfl_xor(mx, 16));
        mx = fmaxf(mx, __shfl_xor(mx, 32));
        const float mn = fmaxf(m2, mx);
        const float al = fast_exp2(m2 - mn);   // first iter: exp2(-inf)=0
        m2 = mn;
        float rs = 0.f;
#pragma unroll
        for (int t = 0; t < 4; ++t)
#pragma unroll
            for (int r = 0; r < 4; ++r) {
                float pe = fast_exp2(p[t][r] - mn);
                p[t][r] = pe;
                rs += pe;
            }
        rs += __shfl_xor(rs, 16);
        rs += __shfl_xor(rs, 32);
        ln = ln * al + rs;

        // broadcast al to this lane's oacc rows (q = g*4+r)
        float alr[4];
#pragma unroll
        for (int r = 0; r < 4; ++r)
            alr[r] = __shfl(al, (lane & 48) | (g * 4 + r));
#pragma unroll
        for (int t2 = 0; t2 < 8; ++t2)
#pragma unroll
            for (int r = 0; r < 4; ++r) oacc[t2][r] *= alr[r];

        // ---- pack P: lane's 16 values ARE its PV A-fragment (via sigma) ----
        unsigned int w[8];
#pragma unroll
        for (int t = 0; t < 4; ++t)
#pragma unroll
            for (int h = 0; h < 2; ++h)
                w[t * 2 + h] = (unsigned int)f2bf(p[t][2 * h]) |
                               ((unsigned int)f2bf(p[t][2 * h + 1]) << 16);
        u32x4 af0 = {w[0], w[1], w[4], w[5]};
        u32x4 af1 = {w[2], w[3], w[6], w[7]};

        // ---- O += P V ----
        {
            s16x8 a0 = __builtin_bit_cast(s16x8, af0);
#pragma unroll
            for (int t2 = 0; t2 < 8; ++t2) {
                s16x8 bv = *(const s16x8*)&lds_vt[(t2 * 16 + c) * VTS + g * 8];
                oacc[t2] = __builtin_amdgcn_mfma_f32_16x16x32_bf16(a0, bv, oacc[t2], 0, 0, 0);
            }
            s16x8 a1 = __builtin_bit_cast(s16x8, af1);
#pragma unroll
            for (int t2 = 0; t2 < 8; ++t2) {
                s16x8 bv = *(const s16x8*)&lds_vt[(t2 * 16 + c) * VTS + 32 + g * 8];
                oacc[t2] = __builtin_amdgcn_mfma_f32_16x16x32_bf16(a1, bv, oacc[t2], 0, 0, 0);
            }
        }
    }

    // ---- write unnormalized partials + stats ----
    {
        const int rowb = (ks * 8 + b) * 2048 + q0 + wave * 16;
#pragma unroll
        for (int t2 = 0; t2 < 8; ++t2)
#pragma unroll
            for (int r = 0; r < 4; ++r)
                opart[(size_t)(rowb + g * 4 + r) * 128 + t2 * 16 + c] = oacc[t2][r];
        if (g == 0) {   // one lane per q-row (lane = c)
            mpart[rowb + c] = m2;
            lpart[rowb + c] = ln;
        }
    }
}

// ---------------- merge the k-split partials ----------------
template <int KSPLIT>
__global__ void merge_parts(const float* __restrict__ opart,
                            const float* __restrict__ mpart,
                            const float* __restrict__ lpart,
                            float* __restrict__ out) {
    const int row = blockIdx.x;
    const int d   = threadIdx.x;
    float m[KSPLIT], l[KSPLIT];
    float M = -INFINITY;
#pragma unroll
    for (int i = 0; i < KSPLIT; ++i) {
        m[i] = mpart[i * 16384 + row];
        l[i] = lpart[i * 16384 + row];
        M = fmaxf(M, m[i]);
    }
    float denom = 0.f, acc = 0.f;
    const size_t base = (size_t)row * 128 + d;
#pragma unroll
    for (int i = 0; i < KSPLIT; ++i) {
        const float a = fast_exp2(m[i] - M);
        denom += a * l[i];
        acc   += a * opart[(size_t)i * 16384 * 128 + base];
    }
    out[base] = acc / denom;
}

extern "C" void kernel_launch(void* const* d_in, const int* in_sizes, int n_in,
                              void* d_out, int out_size, void* d_ws, size_t ws_size,
                              hipStream_t stream) {
    const float* q  = (const float*)d_in[0];
    const float* k  = (const float*)d_in[1];
    const float* v  = (const float*)d_in[2];
    const float* sc = (const float*)d_in[3];
    float* out = (float*)d_out;

    char* ws = (char*)d_ws;
    const size_t MB = 1024 * 1024;
    unsigned short* qh = (unsigned short*)(ws);
    unsigned short* ql = (unsigned short*)(ws + 4 * MB);
    unsigned short* kh = (unsigned short*)(ws + 8 * MB);
    unsigned short* kl = (unsigned short*)(ws + 12 * MB);
    unsigned short* vt = (unsigned short*)(ws + 16 * MB);

    prep<<<4352, 256, 0, stream>>>(q, k, v, qh, ql, kh, kl, vt);

    float* opart = (float*)(ws + 20 * MB);                 // [2][16384][128]
    float* mpart = (float*)(ws + 36 * MB);                 // [2][16384]
    float* lpart = (float*)(ws + 36 * MB + 128 * 1024);    // [2][16384]
    flash_fwd<2><<<512, 256, 0, stream>>>(qh, ql, kh, kl, vt, sc, opart, mpart, lpart);
    merge_parts<2><<<16384, 128, 0, stream>>>(opart, mpart, lpart, out);
}

// Round 8
// 248.866 us; speedup vs baseline: 1.2493x; 1.0332x over previous
//
#include <hip/hip_runtime.h>
#include <hip/hip_bf16.h>

// B=8, LQ=LK=2048, D=128, fp32 in/out, softmax(qk*scale) @ V.
// bf16x3 split QK^T (fp32-accurate logits), fp32 online softmax, bf16 PV.
// R4/R5: swapped QK^T + sigma => lane-local softmax, P stays in registers (85us).
// R6/R7: global_load_lds DMA staging -> container died twice; DMA path dropped.
// R8: keep R6's fragment-major tile images (prep bakes sigma in: all flash
//     LDS traffic is base+lane*16, conflict-free) but stage via ordinary
//     per-lane loads -> ds_write, double-buffered, with the load-issue point
//     pinned right after the barrier by sched_barrier(0) so the compiler
//     cannot sink the loads to their use (R5 failure mode). vmcnt lands
//     after a full compute phase. 48KB LDS => 3 blocks/CU, KSPLIT=3.

typedef float          f32x4 __attribute__((ext_vector_type(4)));
typedef short          s16x8 __attribute__((ext_vector_type(8)));
typedef unsigned int   u32x4 __attribute__((ext_vector_type(4)));
typedef unsigned short u16x4 __attribute__((ext_vector_type(4)));

#define LOG2E 1.4426950408889634f

__device__ __forceinline__ float fast_exp2(float x) {
#if __has_builtin(__builtin_amdgcn_exp2f)
    return __builtin_amdgcn_exp2f(x);
#else
    return exp2f(x);
#endif
}

__device__ __forceinline__ unsigned short f2bf(float x) {
    return __builtin_bit_cast(unsigned short, __float2bfloat16(x));
}
__device__ __forceinline__ float bf2f(unsigned short u) {
    return __bfloat162float(__builtin_bit_cast(__hip_bfloat16, u));
}

// ---------------- fused pre-pass ----------------
// blocks [0,2048):    Q fp32 -> bf16 hi/lo split (linear layout)
// blocks [2048,2560): K+V tile -> fragment-major images, one block per (b,T)
//   K frag f=t*4+kstep, lane(c,g), j:  K[b][32T+8*(c>>2)+(c&3)+4t][32*kstep+8g+j]
//   V frag f=t2,        lane(c,g), j:  V[b][32T+8g+j][16*t2+c]
__global__ void prep(const float* __restrict__ q,
                     const float* __restrict__ k,
                     const float* __restrict__ v,
                     unsigned short* __restrict__ qh,
                     unsigned short* __restrict__ ql,
                     unsigned short* __restrict__ khf,
                     unsigned short* __restrict__ klf,
                     unsigned short* __restrict__ vtf) {
    __shared__ __attribute__((aligned(16))) float smem[2 * 32 * 132];
    const int bb  = blockIdx.x;
    const int tid = threadIdx.x;

    if (bb < 2048) {   // ---- Q hi/lo split ----
        const int i = bb * 256 + tid;
        const float4 val = ((const float4*)q)[i];
        float f[4] = {val.x, val.y, val.z, val.w};
        u16x4 h, l;
#pragma unroll
        for (int j = 0; j < 4; ++j) {
            unsigned short hb = f2bf(f[j]);
            h[j] = hb;
            l[j] = f2bf(f[j] - bf2f(hb));
        }
        ((u16x4*)qh)[i] = h;
        ((u16x4*)ql)[i] = l;
        return;
    }

    // ---- K/V fragment images ----
    float* kt = smem;                 // [32][132]
    float* vt = smem + 32 * 132;      // [32][132]
    const int blk = bb - 2048;
    const int b   = blk >> 6;
    const int T   = blk & 63;
    const size_t rbase = ((size_t)b * 2048 + T * 32) * 128;
#pragma unroll
    for (int p = 0; p < 4; ++p) {
        int idx = p * 256 + tid;           // 0..1023
        int row = idx >> 5, c4 = (idx & 31) * 4;
        *(float4*)&kt[row * 132 + c4] = *(const float4*)&k[rbase + row * 128 + c4];
        *(float4*)&vt[row * 132 + c4] = *(const float4*)&v[rbase + row * 128 + c4];
    }
    __syncthreads();
    const size_t obase = (size_t)(b * 64 + T) * 4096;
#pragma unroll
    for (int p = 0; p < 2; ++p) {
        const int item = p * 256 + tid;    // 0..511
        const int f = item >> 6, lane = item & 63;
        const int c = lane & 15, g = lane >> 4;
        {   // K frag (hi + lo)
            const int t = f >> 2, ks2 = f & 3;
            const int row = 8 * (c >> 2) + (c & 3) + 4 * t;
            const int col = ks2 * 32 + g * 8;
            float vals[8];
            *(float4*)&vals[0] = *(const float4*)&kt[row * 132 + col];
            *(float4*)&vals[4] = *(const float4*)&kt[row * 132 + col + 4];
            unsigned int wh[4], wl[4];
#pragma unroll
            for (int j = 0; j < 4; ++j) {
                unsigned short h0 = f2bf(vals[2 * j]), h1 = f2bf(vals[2 * j + 1]);
                unsigned short l0 = f2bf(vals[2 * j]     - bf2f(h0));
                unsigned short l1 = f2bf(vals[2 * j + 1] - bf2f(h1));
                wh[j] = (unsigned int)h0 | ((unsigned int)h1 << 16);
                wl[j] = (unsigned int)l0 | ((unsigned int)l1 << 16);
            }
            *(u32x4*)&khf[obase + f * 512 + lane * 8] = (u32x4){wh[0], wh[1], wh[2], wh[3]};
            *(u32x4*)&klf[obase + f * 512 + lane * 8] = (u32x4){wl[0], wl[1], wl[2], wl[3]};
        }
        {   // V frag (t2 = f)
            unsigned int wv[4];
#pragma unroll
            for (int j = 0; j < 4; ++j) {
                unsigned short a0 = f2bf(vt[(g * 8 + 2 * j)     * 132 + f * 16 + c]);
                unsigned short a1 = f2bf(vt[(g * 8 + 2 * j + 1) * 132 + f * 16 + c]);
                wv[j] = (unsigned int)a0 | ((unsigned int)a1 << 16);
            }
            *(u32x4*)&vtf[obase + f * 512 + lane * 8] = (u32x4){wv[0], wv[1], wv[2], wv[3]};
        }
    }
}

// ---------------- flash attention main kernel ----------------
// per-buffer LDS: kh 8KB + kl 8KB + vt 8KB; double-buffered = 48KB.

__device__ __forceinline__ void compute_tile(
    const unsigned short* lkh, const unsigned short* lkl,
    const unsigned short* lvt,
    const s16x8 qh[4], const s16x8 ql[4],
    const float4 sv0, const float4 sv1,
    f32x4 oacc[8], float& m2, float& ln,
    const int fb, const int lane) {
    const int g = lane >> 4;
    f32x4 s[2];
    s[0] = (f32x4){0.f, 0.f, 0.f, 0.f};
    s[1] = (f32x4){0.f, 0.f, 0.f, 0.f};
#pragma unroll
    for (int kstep = 0; kstep < 4; ++kstep) {
#pragma unroll
        for (int t = 0; t < 2; ++t) {
            const int off = (t * 4 + kstep) * 512 + fb;
            s16x8 bh = *(const s16x8*)&lkh[off];
            s16x8 bl = *(const s16x8*)&lkl[off];
            s[t] = __builtin_amdgcn_mfma_f32_16x16x32_bf16(bh, qh[kstep], s[t], 0, 0, 0);
            s[t] = __builtin_amdgcn_mfma_f32_16x16x32_bf16(bh, ql[kstep], s[t], 0, 0, 0);
            s[t] = __builtin_amdgcn_mfma_f32_16x16x32_bf16(bl, qh[kstep], s[t], 0, 0, 0);
        }
    }
    // lane owns q-row (c); its 8 values cover k = 8g + 4t + r
    float p[2][4];
    p[0][0] = s[0][0] * (sv0.x * LOG2E); p[0][1] = s[0][1] * (sv0.y * LOG2E);
    p[0][2] = s[0][2] * (sv0.z * LOG2E); p[0][3] = s[0][3] * (sv0.w * LOG2E);
    p[1][0] = s[1][0] * (sv1.x * LOG2E); p[1][1] = s[1][1] * (sv1.y * LOG2E);
    p[1][2] = s[1][2] * (sv1.z * LOG2E); p[1][3] = s[1][3] * (sv1.w * LOG2E);
    float mx = -INFINITY;
#pragma unroll
    for (int t = 0; t < 2; ++t)
#pragma unroll
        for (int r = 0; r < 4; ++r) mx = fmaxf(mx, p[t][r]);
    mx = fmaxf(mx, __shfl_xor(mx, 16));
    mx = fmaxf(mx, __shfl_xor(mx, 32));
    const float mn = fmaxf(m2, mx);
    const float al = fast_exp2(m2 - mn);   // first iter: exp2(-inf)=0
    m2 = mn;
    float rs = 0.f;
#pragma unroll
    for (int t = 0; t < 2; ++t)
#pragma unroll
        for (int r = 0; r < 4; ++r) {
            float pe = fast_exp2(p[t][r] - mn);
            p[t][r] = pe;
            rs += pe;
        }
    rs += __shfl_xor(rs, 16);
    rs += __shfl_xor(rs, 32);
    ln = ln * al + rs;
    float alr[4];
#pragma unroll
    for (int r = 0; r < 4; ++r)
        alr[r] = __shfl(al, (lane & 48) | (g * 4 + r));
#pragma unroll
    for (int t2 = 0; t2 < 8; ++t2)
#pragma unroll
        for (int r = 0; r < 4; ++r) oacc[t2][r] *= alr[r];
    // pack P: lane's 8 values ARE its PV A-fragment
    unsigned int w0 = (unsigned int)f2bf(p[0][0]) | ((unsigned int)f2bf(p[0][1]) << 16);
    unsigned int w1 = (unsigned int)f2bf(p[0][2]) | ((unsigned int)f2bf(p[0][3]) << 16);
    unsigned int w2 = (unsigned int)f2bf(p[1][0]) | ((unsigned int)f2bf(p[1][1]) << 16);
    unsigned int w3 = (unsigned int)f2bf(p[1][2]) | ((unsigned int)f2bf(p[1][3]) << 16);
    u32x4 afu = {w0, w1, w2, w3};
    s16x8 af = __builtin_bit_cast(s16x8, afu);
#pragma unroll
    for (int t2 = 0; t2 < 8; ++t2) {
        s16x8 bv = *(const s16x8*)&lvt[t2 * 512 + fb];
        oacc[t2] = __builtin_amdgcn_mfma_f32_16x16x32_bf16(af, bv, oacc[t2], 0, 0, 0);
    }
}

template <int KSPLIT>
__global__ __launch_bounds__(256, 3)
void flash_fwd(const unsigned short* __restrict__ qh_g,
               const unsigned short* __restrict__ ql_g,
               const unsigned short* __restrict__ khf_g,
               const unsigned short* __restrict__ klf_g,
               const unsigned short* __restrict__ vtf_g,
               const float* __restrict__ scale_g,
               float* __restrict__ opart,
               float* __restrict__ mpart,
               float* __restrict__ lpart) {
    __shared__ __attribute__((aligned(16))) unsigned short khA[4096];
    __shared__ __attribute__((aligned(16))) unsigned short klA[4096];
    __shared__ __attribute__((aligned(16))) unsigned short vtA[4096];
    __shared__ __attribute__((aligned(16))) unsigned short khB[4096];
    __shared__ __attribute__((aligned(16))) unsigned short klB[4096];
    __shared__ __attribute__((aligned(16))) unsigned short vtB[4096];

    const int tid  = threadIdx.x;
    const int wave = tid >> 6;
    const int lane = tid & 63;
    const int c    = lane & 15;
    const int fb   = lane * 8;

    const int bid = blockIdx.x;
    const int b   = bid & 7;            // batch <-> XCD affinity
    const int qt  = (bid >> 3) & 31;
    const int ks  = bid >> 8;           // k-split index
    const int q0  = qt * 64;

    const int TILES = 64;               // 32-row k-tiles
    const int PER   = (TILES + KSPLIT - 1) / KSPLIT;
    const int T0    = ks * PER;
    const int NIT   = min(PER, TILES - T0);   // 22/22/20 or 32/32 (always even)

    const size_t fbase = (size_t)b * 64 * 4096;   // shorts

    // Q fragments (B-operand: col=c -> q row, k=g*8+j -> d)
    s16x8 qh[4], ql[4];
    {
        const int g    = lane >> 4;
        const int qrow = b * 2048 + q0 + wave * 16 + c;
#pragma unroll
        for (int kstep = 0; kstep < 4; ++kstep) {
            int idx = qrow * 16 + kstep * 4 + g;
            qh[kstep] = __builtin_bit_cast(s16x8, ((const u32x4*)qh_g)[idx]);
            ql[kstep] = __builtin_bit_cast(s16x8, ((const u32x4*)ql_g)[idx]);
        }
    }

    // scale base: lane's q-row, 8 contiguous k per tile
    const size_t scb = (size_t)(b * 2048 + q0 + wave * 16 + c) * 2048 + 8 * (lane >> 4);

    f32x4 oacc[8];
#pragma unroll
    for (int t = 0; t < 8; ++t) oacc[t] = (f32x4){0.f, 0.f, 0.f, 0.f};
    float m2 = -INFINITY, ln = 0.f;

    // staging: tile = 3 arrays x 4096 shorts; per thread 2 x 16B per array
    const int o0 = tid * 8, o1 = (256 + tid) * 8;   // short offsets

    u32x4 rg[6];
    auto loadT = [&](int T) {
        const size_t tb = fbase + (size_t)T * 4096;
        rg[0] = *(const u32x4*)&khf_g[tb + o0];
        rg[1] = *(const u32x4*)&khf_g[tb + o1];
        rg[2] = *(const u32x4*)&klf_g[tb + o0];
        rg[3] = *(const u32x4*)&klf_g[tb + o1];
        rg[4] = *(const u32x4*)&vtf_g[tb + o0];
        rg[5] = *(const u32x4*)&vtf_g[tb + o1];
    };
    auto writeT = [&](unsigned short* lkh, unsigned short* lkl, unsigned short* lvt) {
        *(u32x4*)&lkh[o0] = rg[0];  *(u32x4*)&lkh[o1] = rg[1];
        *(u32x4*)&lkl[o0] = rg[2];  *(u32x4*)&lkl[o1] = rg[3];
        *(u32x4*)&lvt[o0] = rg[4];  *(u32x4*)&lvt[o1] = rg[5];
    };

    // prologue: tile T0 -> A
    loadT(T0);
    writeT(khA, klA, vtA);
    float4 sA0 = *(const float4*)&scale_g[scb + (size_t)T0 * 32];
    float4 sA1 = *(const float4*)&scale_g[scb + (size_t)T0 * 32 + 4];

    for (int it = 0; it < NIT; it += 2) {
        const int T = T0 + it;
        __syncthreads();                     // A visible; B free (prev readers done)
        loadT(T + 1);                        // issue next tile's loads (NIT even)
        float4 sB0 = *(const float4*)&scale_g[scb + (size_t)(T + 1) * 32];
        float4 sB1 = *(const float4*)&scale_g[scb + (size_t)(T + 1) * 32 + 4];
        __builtin_amdgcn_sched_barrier(0);   // pin load-issue above the compute
        compute_tile(khA, klA, vtA, qh, ql, sA0, sA1, oacc, m2, ln, fb, lane);
        writeT(khB, klB, vtB);               // vmcnt wait lands here (covered)
        __syncthreads();                     // B visible; A free
        const bool more = (it + 2 < NIT);
        if (more) {
            loadT(T + 2);
            sA0 = *(const float4*)&scale_g[scb + (size_t)(T + 2) * 32];
            sA1 = *(const float4*)&scale_g[scb + (size_t)(T + 2) * 32 + 4];
            __builtin_amdgcn_sched_barrier(0);
        }
        compute_tile(khB, klB, vtB, qh, ql, sB0, sB1, oacc, m2, ln, fb, lane);
        if (more) writeT(khA, klA, vtA);
    }

    // ---- write unnormalized partials + stats ----
    {
        const int g    = lane >> 4;
        const int rowb = (ks * 8 + b) * 2048 + q0 + wave * 16;
#pragma unroll
        for (int t2 = 0; t2 < 8; ++t2)
#pragma unroll
            for (int r = 0; r < 4; ++r)
                opart[(size_t)(rowb + g * 4 + r) * 128 + t2 * 16 + c] = oacc[t2][r];
        if (g == 0) {   // one lane per q-row
            mpart[rowb + c] = m2;
            lpart[rowb + c] = ln;
        }
    }
}

// ---------------- merge the k-split partials ----------------
template <int KSPLIT>
__global__ void merge_parts(const float* __restrict__ opart,
                            const float* __restrict__ mpart,
                            const float* __restrict__ lpart,
                            float* __restrict__ out) {
    const int row = blockIdx.x;
    const int d   = threadIdx.x;
    float m[KSPLIT], l[KSPLIT];
    float M = -INFINITY;
#pragma unroll
    for (int i = 0; i < KSPLIT; ++i) {
        m[i] = mpart[i * 16384 + row];
        l[i] = lpart[i * 16384 + row];
        M = fmaxf(M, m[i]);
    }
    float denom = 0.f, acc = 0.f;
    const size_t base = (size_t)row * 128 + d;
#pragma unroll
    for (int i = 0; i < KSPLIT; ++i) {
        const float a = fast_exp2(m[i] - M);
        denom += a * l[i];
        acc   += a * opart[(size_t)i * 16384 * 128 + base];
    }
    out[base] = acc / denom;
}

extern "C" void kernel_launch(void* const* d_in, const int* in_sizes, int n_in,
                              void* d_out, int out_size, void* d_ws, size_t ws_size,
                              hipStream_t stream) {
    const float* q  = (const float*)d_in[0];
    const float* k  = (const float*)d_in[1];
    const float* v  = (const float*)d_in[2];
    const float* sc = (const float*)d_in[3];
    float* out = (float*)d_out;

    char* ws = (char*)d_ws;
    const size_t MB = 1024 * 1024;
    unsigned short* qh  = (unsigned short*)(ws);
    unsigned short* ql  = (unsigned short*)(ws + 4 * MB);
    unsigned short* khf = (unsigned short*)(ws + 8 * MB);
    unsigned short* klf = (unsigned short*)(ws + 12 * MB);
    unsigned short* vtf = (unsigned short*)(ws + 16 * MB);

    prep<<<2560, 256, 0, stream>>>(q, k, v, qh, ql, khf, klf, vtf);

    const size_t need3 = 44 * MB + 512 * 1024;
    if (ws_size >= need3) {
        float* opart = (float*)(ws + 20 * MB);                 // [3][16384][128]
        float* mpart = (float*)(ws + 44 * MB);                 // [3][16384]
        float* lpart = (float*)(ws + 44 * MB + 256 * 1024);    // [3][16384]
        flash_fwd<3><<<768, 256, 0, stream>>>(qh, ql, khf, klf, vtf, sc, opart, mpart, lpart);
        merge_parts<3><<<16384, 128, 0, stream>>>(opart, mpart, lpart, out);
    } else {
        float* opart = (float*)(ws + 20 * MB);                 // [2][16384][128]
        float* mpart = (float*)(ws + 36 * MB);                 // [2][16384]
        float* lpart = (float*)(ws + 36 * MB + 128 * 1024);    // [2][16384]
        flash_fwd<2><<<512, 256, 0, stream>>>(qh, ql, khf, klf, vtf, sc, opart, mpart, lpart);
        merge_parts<2><<<16384, 128, 0, stream>>>(opart, mpart, lpart, out);
    }
}